// Round 12
// baseline (232.976 us; speedup 1.0000x reference)
//
#include <hip/hip_runtime.h>
#include <hip/hip_bf16.h>

#define TB 4
#define TL 512
#define TD 2880
#define TN 64
#define TKH 8
#define TH 64
#define TG 8
#define TWIN 128
#define TT (TB*TL)

typedef unsigned short u16;
typedef __attribute__((ext_vector_type(8))) short bf16x8;
typedef __attribute__((ext_vector_type(4))) float f32x4;

__device__ __forceinline__ u16 f2b(float f) {
  unsigned u = __float_as_uint(f);
  u += 0x7fffu + ((u >> 16) & 1u);
  return (u16)(u >> 16);
}
__device__ __forceinline__ float b2f(u16 u) {
  return __uint_as_float(((unsigned)u) << 16);
}

__device__ __forceinline__ void load_lds16(const u16* g, u16* l) {
  __builtin_amdgcn_global_load_lds(
      (const __attribute__((address_space(1))) unsigned int*)g,
      (__attribute__((address_space(3))) unsigned int*)l, 16, 0, 0);
}

// ---------------------------------------------------------------------------
// bf16 MFMA GEMM, double-buffered BK=32 (R12): same 24KB LDS as R10 (6
// blocks/CU) but 2 buffers of (128+64)x32, counted s_waitcnt vmcnt(3) so the
// 3 next-tile loads stay in flight across barriers (R5-verified sync shape).
// Swizzle: seg ^= (row>>1)&3 involution (2-way aliasing = free). Row-group-8
// L2 remap (R10-verified). ROPE=1: epilogue applies bias + YaRN RoPE with
// SM_SCALE folded (frag n-mapping {col, col+32} so threads hold the pair).
// ---------------------------------------------------------------------------
template<int BN, int ROPE>
__global__ __launch_bounds__(256, 6) void gemm_db(
    const u16* __restrict__ A, const u16* __restrict__ Bt,
    const float* __restrict__ bias, void* __restrict__ Cv,
    const int* __restrict__ positions,
    int Kd, int Nc, int ldc, int out_bf16, int nx)
{
  constexpr int NF = BN / 32;           // 2 for BN=64
  __shared__ u16 As[2][128*32];         // 2 x 8 KB
  __shared__ u16 Bs[2][BN*32];          // 2 x 4 KB

  const int tid  = threadIdx.x;
  const int lane = tid & 63;
  const int wave = tid >> 6;

  int id = blockIdx.x;
  const int cpx = gridDim.x >> 3;       // gridDim.x % 8 == 0
  id = (id & 7)*cpx + (id >> 3);
  const int rgsz = nx << 3;
  const int rg   = id / rgsz;
  const int rem  = id - rg*rgsz;
  const int bm = (rg*8 + (rem & 7)) * 128;
  const int bn = (rem >> 3) * BN;

  const int wr = (wave >> 1) * 64;
  const int wc = ROPE ? (wave & 1) * 16 : (wave & 1) * (BN/2);
  constexpr int NSTR = ROPE ? 32 : 16;  // frag col stride

  f32x4 acc[4][NF];
#pragma unroll
  for (int i = 0; i < 4; ++i)
#pragma unroll
    for (int j = 0; j < NF; ++j) acc[i][j] = (f32x4){0.f,0.f,0.f,0.f};

  // staging: thread -> row rr (0..63 per issue), 4 chunks of 8 u16 per row.
  // pre-swizzled k-seg (involution on 2 bits of row>>1).
  const int rr   = tid >> 2;
  const int sseg = (tid & 3) ^ ((rr >> 1) & 3);
  const u16* aS = A  + (size_t)(bm + rr)*Kd + sseg*8;
  const u16* bS = Bt + (size_t)(bn + rr)*Kd + sseg*8;

#define STG(dc, kt) do {                                         \
    const int _k0 = (kt) << 5;                                   \
    load_lds16(aS + _k0,                    &As[dc][wave*512]);  \
    load_lds16(aS + (size_t)64*Kd + _k0,    &As[dc][2048 + wave*512]); \
    load_lds16(bS + _k0,                    &Bs[dc][wave*512]);  \
  } while (0)

  const int fr = lane & 15, kq = lane >> 4;
  const int sx = (fr >> 1) & 3;         // (row>>1)&3 == (fr>>1)&3 for frag rows

  const int NT = Kd >> 5;
  STG(0, 0);                            // prologue: 3 loads in flight

  for (int t = 0; t < NT; ++t) {
    const int c = t & 1;
    if (t + 1 < NT) {
      STG(c ^ 1, t + 1);                               // +3 -> 6 outstanding
      asm volatile("s_waitcnt vmcnt(3)" ::: "memory"); // oldest 3 (buf c) done
    } else {
      asm volatile("s_waitcnt vmcnt(0)" ::: "memory");
    }
    __builtin_amdgcn_s_barrier();
    __builtin_amdgcn_sched_barrier(0);

    bf16x8 af[4], bv[NF];
#pragma unroll
    for (int mi = 0; mi < 4; ++mi) {
      const int row = wr + mi*16 + fr;
      af[mi] = *(const bf16x8*)((const char*)&As[c][row*32] + ((kq ^ sx) << 4));
    }
#pragma unroll
    for (int ni = 0; ni < NF; ++ni) {
      const int row = wc + ni*NSTR + fr;
      bv[ni] = *(const bf16x8*)((const char*)&Bs[c][row*32] + ((kq ^ sx) << 4));
    }
    __builtin_amdgcn_s_setprio(1);
#pragma unroll
    for (int mi = 0; mi < 4; ++mi)
#pragma unroll
      for (int ni = 0; ni < NF; ++ni)
        acc[mi][ni] = __builtin_amdgcn_mfma_f32_16x16x32_bf16(
            af[mi], bv[ni], acc[mi][ni], 0, 0, 0);
    __builtin_amdgcn_s_setprio(0);

    __builtin_amdgcn_s_barrier();
    __builtin_amdgcn_sched_barrier(0);
  }
#undef STG

  // epilogue: C/D layout col=lane&15, row=(lane>>4)*4+j (verified R2/R4)
  const int rbase = bm + wr + (lane >> 4)*4;

  if (ROPE) {
    // QKV epilogue: bias + YaRN RoPE (SM_SCALE folded into q rotation).
    // Thread holds pair (col1, col2=col1+32) via NSTR=32 frag mapping.
    const int i = wc + (lane & 15);                  // 0..31 within head
    const int col1 = bn + i, col2 = col1 + 32;
    const int htype = (bn < 4096) ? 0 : (bn < 4608 ? 1 : 2); // q/k/v
    const float b1 = bias[col1], b2 = bias[col2];

    float invf = 0.f, mul = 0.f;
    if (htype < 2) {
      const float lnth = 11.918390573078392f;
      const float low  = 8.092779f;
      const float high = 17.398025f;
      const float conc = 1.3465735903f;
      const float fi = (float)i * 0.03125f;
      const float itp = __expf(-fi * lnth);
      float ramp = ((float)i - low) * (1.0f/(high - low));
      ramp = fminf(fmaxf(ramp, 0.0f), 1.0f);
      invf = itp*(1.0f/32.0f)*ramp + itp*(1.0f - ramp);
      mul = (htype == 0) ? (conc * 0.125f) : conc;
    }

    u16* Cb = (u16*)Cv;
#pragma unroll
    for (int mi = 0; mi < 4; ++mi) {
#pragma unroll
      for (int j = 0; j < 4; ++j) {
        const int row = rbase + mi*16 + j;
        float x1 = acc[mi][0][j] + b1;
        float x2 = acc[mi][1][j] + b2;
        if (htype < 2) {
          const float ang = (float)positions[row] * invf;
          const float cc = cosf(ang) * mul;
          const float ss = sinf(ang) * mul;
          const float y1 = x1*cc - x2*ss;
          const float y2 = x2*cc + x1*ss;
          x1 = y1; x2 = y2;
        }
        Cb[(size_t)row*ldc + col1] = f2b(x1);
        Cb[(size_t)row*ldc + col2] = f2b(x2);
      }
    }
  } else {
    const int cbase = bn + wc + (lane & 15);
#pragma unroll
    for (int mi = 0; mi < 4; ++mi) {
#pragma unroll
      for (int ni = 0; ni < NF; ++ni) {
        const int col = cbase + ni*NSTR;
        const float bvl = (col < Nc) ? bias[col] : 0.f;
#pragma unroll
        for (int j = 0; j < 4; ++j) {
          const int row = rbase + mi*16 + j;
          const float val = acc[mi][ni][j] + bvl;
          if (out_bf16) {
            ((u16*)Cv)[(size_t)row*ldc + col] = f2b(val);
          } else if (col < Nc) {
            ((float*)Cv)[(size_t)row*ldc + col] = val;
          }
        }
      }
    }
  }
}

// ---------------------------------------------------------------------------
// Fused preprocessing (R10-verified).
// ---------------------------------------------------------------------------
__device__ __forceinline__ void tconv_into(
    float (*tile)[33], const float* __restrict__ in, u16* __restrict__ out,
    int R, int C, int bx, int by, int tid)
{
  const int c0 = bx*32, r0 = by*32;
  const int tx = tid & 31, ty = tid >> 5;
#pragma unroll
  for (int i = 0; i < 4; ++i)
    tile[ty + i*8][tx] = in[(size_t)(r0 + ty + i*8)*C + c0 + tx];
  __syncthreads();
#pragma unroll
  for (int i = 0; i < 4; ++i) {
    const int oc = ty + i*8;
    out[(size_t)(c0 + oc)*R + r0 + tx] = f2b(tile[tx][oc]);
  }
}

__global__ __launch_bounds__(256) void prep_kernel(
    const float* __restrict__ x,  const float* __restrict__ wq,
    const float* __restrict__ wk, const float* __restrict__ wv,
    const float* __restrict__ wo, const float* __restrict__ bq,
    const float* __restrict__ bk, const float* __restrict__ bv,
    u16* __restrict__ xb, u16* __restrict__ wqkvt, u16* __restrict__ wot,
    float* __restrict__ bqkv)
{
  __shared__ float tile[32][33];
  const int b = blockIdx.x;
  const int tid = threadIdx.x;

  if (b < 5760) {
    const int i = b*256 + tid;
    float4 f = ((const float4*)x)[i];
    ushort4 o;
    o.x = f2b(f.x); o.y = f2b(f.y); o.z = f2b(f.z); o.w = f2b(f.w);
    ((ushort4*)xb)[i] = o;
  } else if (b < 17280) {
    const int local = b - 5760;
    tconv_into(tile, wq, wqkvt, TD, 4096, local % 128, local / 128, tid);
  } else if (b < 18720) {
    const int local = b - 17280;
    tconv_into(tile, wk, wqkvt + (size_t)4096*TD, TD, 512,
               local % 16, local / 16, tid);
  } else if (b < 20160) {
    const int local = b - 18720;
    tconv_into(tile, wv, wqkvt + (size_t)4608*TD, TD, 512,
               local % 16, local / 16, tid);
  } else if (b < 31680) {
    const int local = b - 20160;
    tconv_into(tile, wo, wot, 4096, TD, local % 90, local / 90, tid);
  } else if (b < 31936) {
    const int i = (b - 31680)*256 + tid;
    ((ushort4*)(wot + (size_t)2880*4096))[i] = (ushort4){0,0,0,0};
  } else {
    const int i = (b - 31936)*256 + tid;
    if (i < 5120)
      bqkv[i] = (i < 4096) ? bq[i] : (i < 4608 ? bk[i-4096] : bv[i-4608]);
  }
}

// ---------------------------------------------------------------------------
// MFMA flash attention (verified R4). Block = (lt, kh, b), 8 waves = GQA head.
// ---------------------------------------------------------------------------
__global__ __launch_bounds__(512) void attn3_kernel(
    const u16* __restrict__ qkv, u16* __restrict__ obuf,
    const float* __restrict__ sinks)
{
  __shared__ u16 Kl[192*64];
  __shared__ u16 Vt[64*192];
  __shared__ u16 Pl[8][2048];

  const int lt = blockIdx.x, kh = blockIdx.y, b = blockIdx.z;
  const int l0 = lt*64;
  const int mstart = (l0 > 127) ? (l0 - 127) : 0;
  const int mcnt = l0 + 64 - mstart;
  const int NC = (mcnt + 31) >> 5;
  const int base = l0 - mstart;

  const int tid = threadIdx.x;
  const int lane = tid & 63;
  const int g = tid >> 6;
  const int lL = lane & 15;
  const int q = lane >> 4;

  {
    const u16* kv0 = qkv + ((size_t)(b*TL + mstart)*5120 + 4096 + kh*64);
    for (int s = tid; s < 1536; s += 512) {
      const int m = s >> 3, hs = s & 7;
      uint4 kx = make_uint4(0,0,0,0), vx = make_uint4(0,0,0,0);
      if (m < mcnt) {
        const u16* gp = kv0 + (size_t)m*5120 + hs*8;
        kx = *(const uint4*)gp;
        vx = *(const uint4*)(gp + 512);
      }
      *(uint4*)((char*)&Kl[m*64] + ((hs*16) ^ ((m&7)<<4))) = kx;
      const unsigned vw[4] = {vx.x, vx.y, vx.z, vx.w};
#pragma unroll
      for (int i = 0; i < 8; ++i) {
        const int h = hs*8 + i;
        const u16 val = (u16)(vw[i>>1] >> ((i&1)*16));
        *(u16*)((char*)&Vt[h*192] + ((m*2) ^ (((h>>3)&7)<<4))) = val;
      }
    }
  }

  bf16x8 qb[4][2];
  {
    const u16* qbase = qkv + ((size_t)(b*TL + l0)*5120 + (kh*8 + g)*64);
#pragma unroll
    for (int l4 = 0; l4 < 4; ++l4)
#pragma unroll
      for (int kk = 0; kk < 2; ++kk)
        qb[l4][kk] = *(const bf16x8*)(qbase + (size_t)(l4*16 + lL)*5120 + kk*32 + q*8);
  }
  const float sink = sinks[kh*8 + g];
  __syncthreads();

  float Mrun[4] = {-1e30f,-1e30f,-1e30f,-1e30f};
  float Dden[4] = {0.f,0.f,0.f,0.f};
  f32x4 oacc[4][4];
#pragma unroll
  for (int i = 0; i < 4; ++i)
#pragma unroll
    for (int j = 0; j < 4; ++j) oacc[i][j] = (f32x4){0.f,0.f,0.f,0.f};

  u16* Pw = &Pl[g][0];

  for (int c = 0; c < NC; ++c) {
    bf16x8 ka[2][2];
#pragma unroll
    for (int m2 = 0; m2 < 2; ++m2) {
      const int row = c*32 + m2*16 + lL;
#pragma unroll
      for (int kk = 0; kk < 2; ++kk)
        ka[m2][kk] = *(const bf16x8*)((char*)&Kl[row*64] +
                       ((kk*64 + q*16) ^ ((row&7)<<4)));
    }
    bf16x8 vb[4];
#pragma unroll
    for (int hf = 0; hf < 4; ++hf) {
      const int h = hf*16 + lL;
      vb[hf] = *(const bf16x8*)((char*)&Vt[h*192] +
                 ((c*64 + q*16) ^ (((h>>3)&7)<<4)));
    }

#pragma unroll
    for (int l4 = 0; l4 < 4; ++l4) {
      const int lo = base + l4*16;
      if (c*32 > lo + 15 || c*32 + 31 < lo - 127) continue;

      const f32x4 z = (f32x4){0.f,0.f,0.f,0.f};
      f32x4 s0 = __builtin_amdgcn_mfma_f32_16x16x32_bf16(ka[0][0], qb[l4][0], z, 0,0,0);
      s0 = __builtin_amdgcn_mfma_f32_16x16x32_bf16(ka[0][1], qb[l4][1], s0, 0,0,0);
      f32x4 s1 = __builtin_amdgcn_mfma_f32_16x16x32_bf16(ka[1][0], qb[l4][0], z, 0,0,0);
      s1 = __builtin_amdgcn_mfma_f32_16x16x32_bf16(ka[1][1], qb[l4][1], s1, 0,0,0);

      float sv[2][4];
      bool  al[2][4];
      float cmax = -1e30f;
#pragma unroll
      for (int m2 = 0; m2 < 2; ++m2)
#pragma unroll
        for (int j = 0; j < 4; ++j) {
          const int delta = (lo + lL) - (c*32 + m2*16 + q*4 + j);
          const bool a = (delta >= 0) && (delta < TWIN);
          const float s = (m2 ? s1[j] : s0[j]);
          sv[m2][j] = s;
          al[m2][j] = a;
          if (a) cmax = fmaxf(cmax, s);
        }
      cmax = fmaxf(cmax, __shfl_xor(cmax, 16));
      cmax = fmaxf(cmax, __shfl_xor(cmax, 32));
      const float Mn = fmaxf(Mrun[l4], cmax);
      const float r = __expf(Mrun[l4] - Mn);
      Mrun[l4] = Mn;

      float ls = 0.f;
      u16 pb[2][4];
#pragma unroll
      for (int m2 = 0; m2 < 2; ++m2)
#pragma unroll
        for (int j = 0; j < 4; ++j) {
          const float p = al[m2][j] ? __expf(sv[m2][j] - Mn) : 0.f;
          ls += p;
          pb[m2][j] = f2b(p);
        }
      ls += __shfl_xor(ls, 16);
      ls += __shfl_xor(ls, 32);
      Dden[l4] = Dden[l4]*r + ls;

      const int l = l4*16 + lL;
#pragma unroll
      for (int m2 = 0; m2 < 2; ++m2) {
        uint2 w;
        w.x = (unsigned)pb[m2][0] | ((unsigned)pb[m2][1] << 16);
        w.y = (unsigned)pb[m2][2] | ((unsigned)pb[m2][3] << 16);
        *(uint2*)((char*)Pw + l*64 + ((m2*32 + q*8) ^ ((l&3)<<4))) = w;
      }

      float rb[4];
#pragma unroll
      for (int j = 0; j < 4; ++j) rb[j] = __shfl(r, q*4 + j);
#pragma unroll
      for (int hf = 0; hf < 4; ++hf)
#pragma unroll
        for (int j = 0; j < 4; ++j) oacc[l4][hf][j] *= rb[j];

      bf16x8 pa = *(const bf16x8*)((char*)Pw + l*64 + ((q*16) ^ ((l&3)<<4)));
#pragma unroll
      for (int hf = 0; hf < 4; ++hf)
        oacc[l4][hf] = __builtin_amdgcn_mfma_f32_16x16x32_bf16(
            pa, vb[hf], oacc[l4][hf], 0, 0, 0);
    }
  }

#pragma unroll
  for (int l4 = 0; l4 < 4; ++l4) {
    const float di = 1.0f / (Dden[l4] + __expf(sink - Mrun[l4]));
    float db[4];
#pragma unroll
    for (int j = 0; j < 4; ++j) db[j] = __shfl(di, q*4 + j);
#pragma unroll
    for (int hf = 0; hf < 4; ++hf)
#pragma unroll
      for (int j = 0; j < 4; ++j) {
        const int row = l0 + l4*16 + q*4 + j;
        obuf[(size_t)(b*TL + row)*4096 + (kh*8 + g)*64 + hf*16 + lL] =
            f2b(oacc[l4][hf][j] * db[j]);
      }
  }
}

// ---------------------------------------------------------------------------
extern "C" void kernel_launch(void* const* d_in, const int* in_sizes, int n_in,
                              void* d_out, int out_size, void* d_ws, size_t ws_size,
                              hipStream_t stream)
{
  const float* x     = (const float*)d_in[0];
  const float* wq    = (const float*)d_in[1];
  const float* bq    = (const float*)d_in[2];
  const float* wk    = (const float*)d_in[3];
  const float* bk    = (const float*)d_in[4];
  const float* wv    = (const float*)d_in[5];
  const float* bv    = (const float*)d_in[6];
  const float* wo    = (const float*)d_in[7];
  const float* bo    = (const float*)d_in[8];
  const float* sinks = (const float*)d_in[9];
  const int* positions = (const int*)d_in[10];
  float* out = (float*)d_out;

  // layout identical to R2/R4/R9/R10 (103.2 MB — verified to fit)
  u16* xb    = (u16*)d_ws;
  u16* wqkvt = xb + (size_t)TT*TD;
  u16* wot   = wqkvt + (size_t)5120*TD;
  u16* qkv   = wot + (size_t)2944*4096;
  u16* obuf  = qkv + (size_t)TT*5120;
  float* bqkv = (float*)(obuf + (size_t)TT*4096);

  // fused preprocessing (1 launch)
  prep_kernel<<<31956, 256, 0, stream>>>(
      x, wq, wk, wv, wo, bq, bk, bv, xb, wqkvt, wot, bqkv);

  // fused QKV projection + bias + RoPE -> bf16 qkv [2048][5120]; 1280 blocks
  gemm_db<64, 1><<<1280, 256, 0, stream>>>(
      xb, wqkvt, bqkv, qkv, positions, TD, 5120, 5120, 1, 80);

  // MFMA flash attention -> obuf [2048][4096]
  attn3_kernel<<<dim3(8, TKH, TB), 512, 0, stream>>>(qkv, obuf, sinks);

  // output projection -> fp32 out [2048][2880]; 720 blocks
  gemm_db<64, 0><<<720, 256, 0, stream>>>(
      obuf, wot, bo, out, nullptr, 4096, 2880, 2880, 0, 45);
}

// Round 13
// 199.467 us; speedup vs baseline: 1.1680x; 1.1680x over previous
//
#include <hip/hip_runtime.h>
#include <hip/hip_bf16.h>

#define TB 4
#define TL 512
#define TD 2880
#define TN 64
#define TKH 8
#define TH 64
#define TG 8
#define TWIN 128
#define TT (TB*TL)

typedef unsigned short u16;
typedef __attribute__((ext_vector_type(8))) short bf16x8;
typedef __attribute__((ext_vector_type(4))) float f32x4;

__device__ __forceinline__ u16 f2b(float f) {
  unsigned u = __float_as_uint(f);
  u += 0x7fffu + ((u >> 16) & 1u);
  return (u16)(u >> 16);
}
__device__ __forceinline__ float b2f(u16 u) {
  return __uint_as_float(((unsigned)u) << 16);
}

__device__ __forceinline__ void load_lds16(const u16* g, u16* l) {
  __builtin_amdgcn_global_load_lds(
      (const __attribute__((address_space(1))) unsigned int*)g,
      (__attribute__((address_space(3))) unsigned int*)l, 16, 0, 0);
}

// ---------------------------------------------------------------------------
// bf16 MFMA GEMM (R9/R10-verified core). BM=128 x BN=64, BK=64, 24KB LDS
// single-buffered, involution swizzle (0 conflicts), row-group-8 L2 remap.
// R13: ROPE=1 grafts the R12-verified bias+YaRN-RoPE epilogue (SM_SCALE
// folded into q rotation); frag n-mapping {col, col+32} so each thread
// holds the rotation pair. ROPE=0 is the plain verified bias epilogue.
// ---------------------------------------------------------------------------
template<int BN, int ROPE>
__global__ __launch_bounds__(256, 4) void gemm_sn(
    const u16* __restrict__ A, const u16* __restrict__ Bt,
    const float* __restrict__ bias, void* __restrict__ Cv,
    const int* __restrict__ positions,
    int Kd, int Nc, int ldc, int out_bf16, int nx)
{
  constexpr int NF = BN / 32;           // 2 for BN=64
  __shared__ u16 As[128*64];            // 16 KB
  __shared__ u16 Bs[BN*64];             // 8 KB

  const int tid  = threadIdx.x;
  const int lane = tid & 63;
  const int wave = tid >> 6;

  int id = blockIdx.x;
  const int cpx = gridDim.x >> 3;       // gridDim.x % 8 == 0
  id = (id & 7)*cpx + (id >> 3);
  const int rgsz = nx << 3;
  const int rg   = id / rgsz;
  const int rem  = id - rg*rgsz;
  const int bm = (rg*8 + (rem & 7)) * 128;
  const int bn = (rem >> 3) * BN;

  const int wr = (wave >> 1) * 64;
  const int wc = ROPE ? (wave & 1) * 16 : (wave & 1) * (BN/2);
  constexpr int NSTR = ROPE ? 32 : 16;  // frag col stride

  f32x4 acc[4][NF];
#pragma unroll
  for (int i = 0; i < 4; ++i)
#pragma unroll
    for (int j = 0; j < NF; ++j) acc[i][j] = (f32x4){0.f,0.f,0.f,0.f};

  // staging: thread -> row rr (0..31 per issue; 2048 u16 per issue),
  // pre-swizzled k-seg (involution)
  const int rr   = tid >> 3;
  const int sseg = (tid & 7) ^ (rr & 7);
  const u16* aS = A  + (size_t)(bm + rr)*Kd + sseg*8;
  const u16* bS = Bt + (size_t)(bn + rr)*Kd + sseg*8;

  const int fr = lane & 15, kq = lane >> 4;
  const int swz = lane & 7;             // frag row&7 == lane&7

  const int NT = Kd >> 6;
  for (int t = 0; t < NT; ++t) {
    const int k0 = t << 6;
#pragma unroll
    for (int i = 0; i < 4; ++i)
      load_lds16(aS + (size_t)i*32*Kd + k0, &As[i*2048 + wave*512]);
#pragma unroll
    for (int i = 0; i < BN/32; ++i)
      load_lds16(bS + (size_t)i*32*Kd + k0, &Bs[i*2048 + wave*512]);
    __syncthreads();

#pragma unroll
    for (int s = 0; s < 2; ++s) {
      const int ch = ((s*4 + kq) ^ swz) * 16;
      bf16x8 af[4], bv[NF];
#pragma unroll
      for (int mi = 0; mi < 4; ++mi) {
        const int row = wr + mi*16 + fr;
        af[mi] = *(const bf16x8*)((const char*)&As[row*64] + ch);
      }
#pragma unroll
      for (int ni = 0; ni < NF; ++ni) {
        const int row = wc + ni*NSTR + fr;
        bv[ni] = *(const bf16x8*)((const char*)&Bs[row*64] + ch);
      }
#pragma unroll
      for (int mi = 0; mi < 4; ++mi)
#pragma unroll
        for (int ni = 0; ni < NF; ++ni)
          acc[mi][ni] = __builtin_amdgcn_mfma_f32_16x16x32_bf16(
              af[mi], bv[ni], acc[mi][ni], 0, 0, 0);
    }
    __syncthreads();
  }

  // epilogue: C/D layout col=lane&15, row=(lane>>4)*4+j (verified R2/R4)
  const int rbase = bm + wr + (lane >> 4)*4;

  if (ROPE) {
    // R12-verified: bias + YaRN RoPE, SM_SCALE folded into q rotation.
    const int i = wc + (lane & 15);                  // 0..31 within head
    const int col1 = bn + i, col2 = col1 + 32;
    const int htype = (bn < 4096) ? 0 : (bn < 4608 ? 1 : 2); // q/k/v
    const float b1 = bias[col1], b2 = bias[col2];

    float invf = 0.f, mul = 0.f;
    if (htype < 2) {
      const float lnth = 11.918390573078392f;
      const float low  = 8.092779f;
      const float high = 17.398025f;
      const float conc = 1.3465735903f;
      const float fi = (float)i * 0.03125f;
      const float itp = __expf(-fi * lnth);
      float ramp = ((float)i - low) * (1.0f/(high - low));
      ramp = fminf(fmaxf(ramp, 0.0f), 1.0f);
      invf = itp*(1.0f/32.0f)*ramp + itp*(1.0f - ramp);
      mul = (htype == 0) ? (conc * 0.125f) : conc;
    }

    u16* Cb = (u16*)Cv;
#pragma unroll
    for (int mi = 0; mi < 4; ++mi) {
#pragma unroll
      for (int j = 0; j < 4; ++j) {
        const int row = rbase + mi*16 + j;
        float x1 = acc[mi][0][j] + b1;
        float x2 = acc[mi][1][j] + b2;
        if (htype < 2) {
          const float ang = (float)positions[row] * invf;
          const float cc = cosf(ang) * mul;
          const float ss = sinf(ang) * mul;
          const float y1 = x1*cc - x2*ss;
          const float y2 = x2*cc + x1*ss;
          x1 = y1; x2 = y2;
        }
        Cb[(size_t)row*ldc + col1] = f2b(x1);
        Cb[(size_t)row*ldc + col2] = f2b(x2);
      }
    }
  } else {
    const int cbase = bn + wc + (lane & 15);
#pragma unroll
    for (int mi = 0; mi < 4; ++mi) {
#pragma unroll
      for (int ni = 0; ni < NF; ++ni) {
        const int col = cbase + ni*NSTR;
        const float bvl = (col < Nc) ? bias[col] : 0.f;
#pragma unroll
        for (int j = 0; j < 4; ++j) {
          const int row = rbase + mi*16 + j;
          const float val = acc[mi][ni][j] + bvl;
          if (out_bf16) {
            ((u16*)Cv)[(size_t)row*ldc + col] = f2b(val);
          } else if (col < Nc) {
            ((float*)Cv)[(size_t)row*ldc + col] = val;
          }
        }
      }
    }
  }
}

// ---------------------------------------------------------------------------
// Fused preprocessing (R10-verified).
// ---------------------------------------------------------------------------
__device__ __forceinline__ void tconv_into(
    float (*tile)[33], const float* __restrict__ in, u16* __restrict__ out,
    int R, int C, int bx, int by, int tid)
{
  const int c0 = bx*32, r0 = by*32;
  const int tx = tid & 31, ty = tid >> 5;
#pragma unroll
  for (int i = 0; i < 4; ++i)
    tile[ty + i*8][tx] = in[(size_t)(r0 + ty + i*8)*C + c0 + tx];
  __syncthreads();
#pragma unroll
  for (int i = 0; i < 4; ++i) {
    const int oc = ty + i*8;
    out[(size_t)(c0 + oc)*R + r0 + tx] = f2b(tile[tx][oc]);
  }
}

__global__ __launch_bounds__(256) void prep_kernel(
    const float* __restrict__ x,  const float* __restrict__ wq,
    const float* __restrict__ wk, const float* __restrict__ wv,
    const float* __restrict__ wo, const float* __restrict__ bq,
    const float* __restrict__ bk, const float* __restrict__ bv,
    u16* __restrict__ xb, u16* __restrict__ wqkvt, u16* __restrict__ wot,
    float* __restrict__ bqkv)
{
  __shared__ float tile[32][33];
  const int b = blockIdx.x;
  const int tid = threadIdx.x;

  if (b < 5760) {
    const int i = b*256 + tid;
    float4 f = ((const float4*)x)[i];
    ushort4 o;
    o.x = f2b(f.x); o.y = f2b(f.y); o.z = f2b(f.z); o.w = f2b(f.w);
    ((ushort4*)xb)[i] = o;
  } else if (b < 17280) {
    const int local = b - 5760;
    tconv_into(tile, wq, wqkvt, TD, 4096, local % 128, local / 128, tid);
  } else if (b < 18720) {
    const int local = b - 17280;
    tconv_into(tile, wk, wqkvt + (size_t)4096*TD, TD, 512,
               local % 16, local / 16, tid);
  } else if (b < 20160) {
    const int local = b - 18720;
    tconv_into(tile, wv, wqkvt + (size_t)4608*TD, TD, 512,
               local % 16, local / 16, tid);
  } else if (b < 31680) {
    const int local = b - 20160;
    tconv_into(tile, wo, wot, 4096, TD, local % 90, local / 90, tid);
  } else if (b < 31936) {
    const int i = (b - 31680)*256 + tid;
    ((ushort4*)(wot + (size_t)2880*4096))[i] = (ushort4){0,0,0,0};
  } else {
    const int i = (b - 31936)*256 + tid;
    if (i < 5120)
      bqkv[i] = (i < 4096) ? bq[i] : (i < 4608 ? bk[i-4096] : bv[i-4608]);
  }
}

// ---------------------------------------------------------------------------
// MFMA flash attention (verified R4). Block = (lt, kh, b), 8 waves = GQA head.
// ---------------------------------------------------------------------------
__global__ __launch_bounds__(512) void attn3_kernel(
    const u16* __restrict__ qkv, u16* __restrict__ obuf,
    const float* __restrict__ sinks)
{
  __shared__ u16 Kl[192*64];
  __shared__ u16 Vt[64*192];
  __shared__ u16 Pl[8][2048];

  const int lt = blockIdx.x, kh = blockIdx.y, b = blockIdx.z;
  const int l0 = lt*64;
  const int mstart = (l0 > 127) ? (l0 - 127) : 0;
  const int mcnt = l0 + 64 - mstart;
  const int NC = (mcnt + 31) >> 5;
  const int base = l0 - mstart;

  const int tid = threadIdx.x;
  const int lane = tid & 63;
  const int g = tid >> 6;
  const int lL = lane & 15;
  const int q = lane >> 4;

  {
    const u16* kv0 = qkv + ((size_t)(b*TL + mstart)*5120 + 4096 + kh*64);
    for (int s = tid; s < 1536; s += 512) {
      const int m = s >> 3, hs = s & 7;
      uint4 kx = make_uint4(0,0,0,0), vx = make_uint4(0,0,0,0);
      if (m < mcnt) {
        const u16* gp = kv0 + (size_t)m*5120 + hs*8;
        kx = *(const uint4*)gp;
        vx = *(const uint4*)(gp + 512);
      }
      *(uint4*)((char*)&Kl[m*64] + ((hs*16) ^ ((m&7)<<4))) = kx;
      const unsigned vw[4] = {vx.x, vx.y, vx.z, vx.w};
#pragma unroll
      for (int i = 0; i < 8; ++i) {
        const int h = hs*8 + i;
        const u16 val = (u16)(vw[i>>1] >> ((i&1)*16));
        *(u16*)((char*)&Vt[h*192] + ((m*2) ^ (((h>>3)&7)<<4))) = val;
      }
    }
  }

  bf16x8 qb[4][2];
  {
    const u16* qbase = qkv + ((size_t)(b*TL + l0)*5120 + (kh*8 + g)*64);
#pragma unroll
    for (int l4 = 0; l4 < 4; ++l4)
#pragma unroll
      for (int kk = 0; kk < 2; ++kk)
        qb[l4][kk] = *(const bf16x8*)(qbase + (size_t)(l4*16 + lL)*5120 + kk*32 + q*8);
  }
  const float sink = sinks[kh*8 + g];
  __syncthreads();

  float Mrun[4] = {-1e30f,-1e30f,-1e30f,-1e30f};
  float Dden[4] = {0.f,0.f,0.f,0.f};
  f32x4 oacc[4][4];
#pragma unroll
  for (int i = 0; i < 4; ++i)
#pragma unroll
    for (int j = 0; j < 4; ++j) oacc[i][j] = (f32x4){0.f,0.f,0.f,0.f};

  u16* Pw = &Pl[g][0];

  for (int c = 0; c < NC; ++c) {
    bf16x8 ka[2][2];
#pragma unroll
    for (int m2 = 0; m2 < 2; ++m2) {
      const int row = c*32 + m2*16 + lL;
#pragma unroll
      for (int kk = 0; kk < 2; ++kk)
        ka[m2][kk] = *(const bf16x8*)((char*)&Kl[row*64] +
                       ((kk*64 + q*16) ^ ((row&7)<<4)));
    }
    bf16x8 vb[4];
#pragma unroll
    for (int hf = 0; hf < 4; ++hf) {
      const int h = hf*16 + lL;
      vb[hf] = *(const bf16x8*)((char*)&Vt[h*192] +
                 ((c*64 + q*16) ^ (((h>>3)&7)<<4)));
    }

#pragma unroll
    for (int l4 = 0; l4 < 4; ++l4) {
      const int lo = base + l4*16;
      if (c*32 > lo + 15 || c*32 + 31 < lo - 127) continue;

      const f32x4 z = (f32x4){0.f,0.f,0.f,0.f};
      f32x4 s0 = __builtin_amdgcn_mfma_f32_16x16x32_bf16(ka[0][0], qb[l4][0], z, 0,0,0);
      s0 = __builtin_amdgcn_mfma_f32_16x16x32_bf16(ka[0][1], qb[l4][1], s0, 0,0,0);
      f32x4 s1 = __builtin_amdgcn_mfma_f32_16x16x32_bf16(ka[1][0], qb[l4][0], z, 0,0,0);
      s1 = __builtin_amdgcn_mfma_f32_16x16x32_bf16(ka[1][1], qb[l4][1], s1, 0,0,0);

      float sv[2][4];
      bool  al[2][4];
      float cmax = -1e30f;
#pragma unroll
      for (int m2 = 0; m2 < 2; ++m2)
#pragma unroll
        for (int j = 0; j < 4; ++j) {
          const int delta = (lo + lL) - (c*32 + m2*16 + q*4 + j);
          const bool a = (delta >= 0) && (delta < TWIN);
          const float s = (m2 ? s1[j] : s0[j]);
          sv[m2][j] = s;
          al[m2][j] = a;
          if (a) cmax = fmaxf(cmax, s);
        }
      cmax = fmaxf(cmax, __shfl_xor(cmax, 16));
      cmax = fmaxf(cmax, __shfl_xor(cmax, 32));
      const float Mn = fmaxf(Mrun[l4], cmax);
      const float r = __expf(Mrun[l4] - Mn);
      Mrun[l4] = Mn;

      float ls = 0.f;
      u16 pb[2][4];
#pragma unroll
      for (int m2 = 0; m2 < 2; ++m2)
#pragma unroll
        for (int j = 0; j < 4; ++j) {
          const float p = al[m2][j] ? __expf(sv[m2][j] - Mn) : 0.f;
          ls += p;
          pb[m2][j] = f2b(p);
        }
      ls += __shfl_xor(ls, 16);
      ls += __shfl_xor(ls, 32);
      Dden[l4] = Dden[l4]*r + ls;

      const int l = l4*16 + lL;
#pragma unroll
      for (int m2 = 0; m2 < 2; ++m2) {
        uint2 w;
        w.x = (unsigned)pb[m2][0] | ((unsigned)pb[m2][1] << 16);
        w.y = (unsigned)pb[m2][2] | ((unsigned)pb[m2][3] << 16);
        *(uint2*)((char*)Pw + l*64 + ((m2*32 + q*8) ^ ((l&3)<<4))) = w;
      }

      float rb[4];
#pragma unroll
      for (int j = 0; j < 4; ++j) rb[j] = __shfl(r, q*4 + j);
#pragma unroll
      for (int hf = 0; hf < 4; ++hf)
#pragma unroll
        for (int j = 0; j < 4; ++j) oacc[l4][hf][j] *= rb[j];

      bf16x8 pa = *(const bf16x8*)((char*)Pw + l*64 + ((q*16) ^ ((l&3)<<4)));
#pragma unroll
      for (int hf = 0; hf < 4; ++hf)
        oacc[l4][hf] = __builtin_amdgcn_mfma_f32_16x16x32_bf16(
            pa, vb[hf], oacc[l4][hf], 0, 0, 0);
    }
  }

#pragma unroll
  for (int l4 = 0; l4 < 4; ++l4) {
    const float di = 1.0f / (Dden[l4] + __expf(sink - Mrun[l4]));
    float db[4];
#pragma unroll
    for (int j = 0; j < 4; ++j) db[j] = __shfl(di, q*4 + j);
#pragma unroll
    for (int hf = 0; hf < 4; ++hf)
#pragma unroll
      for (int j = 0; j < 4; ++j) {
        const int row = l0 + l4*16 + q*4 + j;
        obuf[(size_t)(b*TL + row)*4096 + (kh*8 + g)*64 + hf*16 + lL] =
            f2b(oacc[l4][hf][j] * db[j]);
      }
  }
}

// ---------------------------------------------------------------------------
extern "C" void kernel_launch(void* const* d_in, const int* in_sizes, int n_in,
                              void* d_out, int out_size, void* d_ws, size_t ws_size,
                              hipStream_t stream)
{
  const float* x     = (const float*)d_in[0];
  const float* wq    = (const float*)d_in[1];
  const float* bq    = (const float*)d_in[2];
  const float* wk    = (const float*)d_in[3];
  const float* bk    = (const float*)d_in[4];
  const float* wv    = (const float*)d_in[5];
  const float* bv    = (const float*)d_in[6];
  const float* wo    = (const float*)d_in[7];
  const float* bo    = (const float*)d_in[8];
  const float* sinks = (const float*)d_in[9];
  const int* positions = (const int*)d_in[10];
  float* out = (float*)d_out;

  // layout identical to R2/R4/R9/R10 (103.2 MB — verified to fit)
  u16* xb    = (u16*)d_ws;
  u16* wqkvt = xb + (size_t)TT*TD;
  u16* wot   = wqkvt + (size_t)5120*TD;
  u16* qkv   = wot + (size_t)2944*4096;
  u16* obuf  = qkv + (size_t)TT*5120;
  float* bqkv = (float*)(obuf + (size_t)TT*4096);

  // fused preprocessing (1 launch)
  prep_kernel<<<31956, 256, 0, stream>>>(
      x, wq, wk, wv, wo, bq, bk, bv, xb, wqkvt, wot, bqkv);

  // fused QKV projection + bias + RoPE -> bf16 qkv [2048][5120]; 1280 blocks
  gemm_sn<64, 1><<<1280, 256, 0, stream>>>(
      xb, wqkvt, bqkv, qkv, positions, TD, 5120, 5120, 1, 80);

  // MFMA flash attention -> obuf [2048][4096]
  attn3_kernel<<<dim3(8, TKH, TB), 512, 0, stream>>>(qkv, obuf, sinks);

  // output projection -> fp32 out [2048][2880]; 720 blocks
  gemm_sn<64, 0><<<720, 256, 0, stream>>>(
      obuf, wot, bo, out, nullptr, 4096, 2880, 2880, 0, 45);
}

// Round 14
// 191.690 us; speedup vs baseline: 1.2154x; 1.0406x over previous
//
#include <hip/hip_runtime.h>
#include <hip/hip_bf16.h>

#define TB 4
#define TL 512
#define TD 2880
#define TN 64
#define TKH 8
#define TH 64
#define TG 8
#define TWIN 128
#define TT (TB*TL)

typedef unsigned short u16;
typedef __attribute__((ext_vector_type(8))) short bf16x8;
typedef __attribute__((ext_vector_type(4))) float f32x4;

__device__ __forceinline__ u16 f2b(float f) {
  unsigned u = __float_as_uint(f);
  u += 0x7fffu + ((u >> 16) & 1u);
  return (u16)(u >> 16);
}
__device__ __forceinline__ float b2f(u16 u) {
  return __uint_as_float(((unsigned)u) << 16);
}

__device__ __forceinline__ void load_lds16(const u16* g, u16* l) {
  __builtin_amdgcn_global_load_lds(
      (const __attribute__((address_space(1))) unsigned int*)g,
      (__attribute__((address_space(3))) unsigned int*)l, 16, 0, 0);
}

// ---------------------------------------------------------------------------
// bf16 MFMA GEMM (R9/R10-verified core). BM=128 x BN, BK=64, single-buffered
// LDS (16 + BN/4 KB), involution swizzle (0 conflicts), row-group-8 L2 remap.
// R14: BN=128 for QKV (64 MFMA per wave per K-tile vs 32 — doubles the
// MFMA:stall ratio per period at +33% staged bytes). ROPE epilogue
// generalized to NF/2 rotation pairs (p=0 path is byte-identical to the
// R13-verified NF=2 case).
// ---------------------------------------------------------------------------
template<int BN, int ROPE>
__global__ __launch_bounds__(256, 4) void gemm_sn(
    const u16* __restrict__ A, const u16* __restrict__ Bt,
    const float* __restrict__ bias, void* __restrict__ Cv,
    const int* __restrict__ positions,
    int Kd, int Nc, int ldc, int out_bf16, int nx)
{
  constexpr int NF = BN / 32;           // 2 for BN=64, 4 for BN=128
  __shared__ u16 As[128*64];            // 16 KB
  __shared__ u16 Bs[BN*64];             // 8 or 16 KB

  const int tid  = threadIdx.x;
  const int lane = tid & 63;
  const int wave = tid >> 6;

  int id = blockIdx.x;
  const int cpx = gridDim.x >> 3;       // gridDim.x % 8 == 0
  id = (id & 7)*cpx + (id >> 3);
  const int rgsz = nx << 3;
  const int rg   = id / rgsz;
  const int rem  = id - rg*rgsz;
  const int bm = (rg*8 + (rem & 7)) * 128;
  const int bn = (rem >> 3) * BN;

  const int wr = (wave >> 1) * 64;
  const int wc = ROPE ? (wave & 1) * 16 : (wave & 1) * (BN/2);
  constexpr int NSTR = ROPE ? 32 : 16;  // frag col stride

  f32x4 acc[4][NF];
#pragma unroll
  for (int i = 0; i < 4; ++i)
#pragma unroll
    for (int j = 0; j < NF; ++j) acc[i][j] = (f32x4){0.f,0.f,0.f,0.f};

  // staging: thread -> row rr (0..31 per issue; 2048 u16 per issue),
  // pre-swizzled k-seg (involution)
  const int rr   = tid >> 3;
  const int sseg = (tid & 7) ^ (rr & 7);
  const u16* aS = A  + (size_t)(bm + rr)*Kd + sseg*8;
  const u16* bS = Bt + (size_t)(bn + rr)*Kd + sseg*8;

  const int fr = lane & 15, kq = lane >> 4;
  const int swz = lane & 7;             // frag row&7 == lane&7

  const int NT = Kd >> 6;
  for (int t = 0; t < NT; ++t) {
    const int k0 = t << 6;
#pragma unroll
    for (int i = 0; i < 4; ++i)
      load_lds16(aS + (size_t)i*32*Kd + k0, &As[i*2048 + wave*512]);
#pragma unroll
    for (int i = 0; i < BN/32; ++i)
      load_lds16(bS + (size_t)i*32*Kd + k0, &Bs[i*2048 + wave*512]);
    __syncthreads();

#pragma unroll
    for (int s = 0; s < 2; ++s) {
      const int ch = ((s*4 + kq) ^ swz) * 16;
      bf16x8 af[4], bv[NF];
#pragma unroll
      for (int mi = 0; mi < 4; ++mi) {
        const int row = wr + mi*16 + fr;
        af[mi] = *(const bf16x8*)((const char*)&As[row*64] + ch);
      }
#pragma unroll
      for (int ni = 0; ni < NF; ++ni) {
        const int row = wc + ni*NSTR + fr;
        bv[ni] = *(const bf16x8*)((const char*)&Bs[row*64] + ch);
      }
#pragma unroll
      for (int mi = 0; mi < 4; ++mi)
#pragma unroll
        for (int ni = 0; ni < NF; ++ni)
          acc[mi][ni] = __builtin_amdgcn_mfma_f32_16x16x32_bf16(
              af[mi], bv[ni], acc[mi][ni], 0, 0, 0);
    }
    __syncthreads();
  }

  // epilogue: C/D layout col=lane&15, row=(lane>>4)*4+j (verified R2/R4)
  const int rbase = bm + wr + (lane >> 4)*4;

  if (ROPE) {
    // R12/R13-verified rotation, generalized to NF/2 pairs.
    // Pair p: cols (bn + p*64 + i, +32) from acc[mi][2p], acc[mi][2p+1].
    constexpr int NP = NF / 2;
    const int i = wc + (lane & 15);                  // 0..31 within head
    const float lnth = 11.918390573078392f;
    const float low  = 8.092779f;
    const float high = 17.398025f;
    const float conc = 1.3465735903f;
    const float fi = (float)i * 0.03125f;
    const float itp = __expf(-fi * lnth);
    float ramp = ((float)i - low) * (1.0f/(high - low));
    ramp = fminf(fmaxf(ramp, 0.0f), 1.0f);
    const float invf = itp*(1.0f/32.0f)*ramp + itp*(1.0f - ramp);

    u16* Cb = (u16*)Cv;
#pragma unroll
    for (int p = 0; p < NP; ++p) {
      const int hb = bn + p*64;                      // head base col
      const int col1 = hb + i, col2 = col1 + 32;
      const int htype = (hb < 4096) ? 0 : (hb < 4608 ? 1 : 2); // q/k/v
      const float mul = (htype == 0) ? (conc * 0.125f) : conc;
      const float b1 = bias[col1], b2 = bias[col2];
#pragma unroll
      for (int mi = 0; mi < 4; ++mi) {
#pragma unroll
        for (int j = 0; j < 4; ++j) {
          const int row = rbase + mi*16 + j;
          float x1 = acc[mi][2*p+0][j] + b1;
          float x2 = acc[mi][2*p+1][j] + b2;
          if (htype < 2) {
            const float ang = (float)positions[row] * invf;
            const float cc = cosf(ang) * mul;
            const float ss = sinf(ang) * mul;
            const float y1 = x1*cc - x2*ss;
            const float y2 = x2*cc + x1*ss;
            x1 = y1; x2 = y2;
          }
          Cb[(size_t)row*ldc + col1] = f2b(x1);
          Cb[(size_t)row*ldc + col2] = f2b(x2);
        }
      }
    }
  } else {
    const int cbase = bn + wc + (lane & 15);
#pragma unroll
    for (int mi = 0; mi < 4; ++mi) {
#pragma unroll
      for (int ni = 0; ni < NF; ++ni) {
        const int col = cbase + ni*NSTR;
        const float bvl = (col < Nc) ? bias[col] : 0.f;
#pragma unroll
        for (int j = 0; j < 4; ++j) {
          const int row = rbase + mi*16 + j;
          const float val = acc[mi][ni][j] + bvl;
          if (out_bf16) {
            ((u16*)Cv)[(size_t)row*ldc + col] = f2b(val);
          } else if (col < Nc) {
            ((float*)Cv)[(size_t)row*ldc + col] = val;
          }
        }
      }
    }
  }
}

// ---------------------------------------------------------------------------
// Fused preprocessing (R10-verified).
// ---------------------------------------------------------------------------
__device__ __forceinline__ void tconv_into(
    float (*tile)[33], const float* __restrict__ in, u16* __restrict__ out,
    int R, int C, int bx, int by, int tid)
{
  const int c0 = bx*32, r0 = by*32;
  const int tx = tid & 31, ty = tid >> 5;
#pragma unroll
  for (int i = 0; i < 4; ++i)
    tile[ty + i*8][tx] = in[(size_t)(r0 + ty + i*8)*C + c0 + tx];
  __syncthreads();
#pragma unroll
  for (int i = 0; i < 4; ++i) {
    const int oc = ty + i*8;
    out[(size_t)(c0 + oc)*R + r0 + tx] = f2b(tile[tx][oc]);
  }
}

__global__ __launch_bounds__(256) void prep_kernel(
    const float* __restrict__ x,  const float* __restrict__ wq,
    const float* __restrict__ wk, const float* __restrict__ wv,
    const float* __restrict__ wo, const float* __restrict__ bq,
    const float* __restrict__ bk, const float* __restrict__ bv,
    u16* __restrict__ xb, u16* __restrict__ wqkvt, u16* __restrict__ wot,
    float* __restrict__ bqkv)
{
  __shared__ float tile[32][33];
  const int b = blockIdx.x;
  const int tid = threadIdx.x;

  if (b < 5760) {
    const int i = b*256 + tid;
    float4 f = ((const float4*)x)[i];
    ushort4 o;
    o.x = f2b(f.x); o.y = f2b(f.y); o.z = f2b(f.z); o.w = f2b(f.w);
    ((ushort4*)xb)[i] = o;
  } else if (b < 17280) {
    const int local = b - 5760;
    tconv_into(tile, wq, wqkvt, TD, 4096, local % 128, local / 128, tid);
  } else if (b < 18720) {
    const int local = b - 17280;
    tconv_into(tile, wk, wqkvt + (size_t)4096*TD, TD, 512,
               local % 16, local / 16, tid);
  } else if (b < 20160) {
    const int local = b - 18720;
    tconv_into(tile, wv, wqkvt + (size_t)4608*TD, TD, 512,
               local % 16, local / 16, tid);
  } else if (b < 31680) {
    const int local = b - 20160;
    tconv_into(tile, wo, wot, 4096, TD, local % 90, local / 90, tid);
  } else if (b < 31936) {
    const int i = (b - 31680)*256 + tid;
    ((ushort4*)(wot + (size_t)2880*4096))[i] = (ushort4){0,0,0,0};
  } else {
    const int i = (b - 31936)*256 + tid;
    if (i < 5120)
      bqkv[i] = (i < 4096) ? bq[i] : (i < 4608 ? bk[i-4096] : bv[i-4608]);
  }
}

// ---------------------------------------------------------------------------
// MFMA flash attention (verified R4). Block = (lt, kh, b), 8 waves = GQA head.
// ---------------------------------------------------------------------------
__global__ __launch_bounds__(512) void attn3_kernel(
    const u16* __restrict__ qkv, u16* __restrict__ obuf,
    const float* __restrict__ sinks)
{
  __shared__ u16 Kl[192*64];
  __shared__ u16 Vt[64*192];
  __shared__ u16 Pl[8][2048];

  const int lt = blockIdx.x, kh = blockIdx.y, b = blockIdx.z;
  const int l0 = lt*64;
  const int mstart = (l0 > 127) ? (l0 - 127) : 0;
  const int mcnt = l0 + 64 - mstart;
  const int NC = (mcnt + 31) >> 5;
  const int base = l0 - mstart;

  const int tid = threadIdx.x;
  const int lane = tid & 63;
  const int g = tid >> 6;
  const int lL = lane & 15;
  const int q = lane >> 4;

  {
    const u16* kv0 = qkv + ((size_t)(b*TL + mstart)*5120 + 4096 + kh*64);
    for (int s = tid; s < 1536; s += 512) {
      const int m = s >> 3, hs = s & 7;
      uint4 kx = make_uint4(0,0,0,0), vx = make_uint4(0,0,0,0);
      if (m < mcnt) {
        const u16* gp = kv0 + (size_t)m*5120 + hs*8;
        kx = *(const uint4*)gp;
        vx = *(const uint4*)(gp + 512);
      }
      *(uint4*)((char*)&Kl[m*64] + ((hs*16) ^ ((m&7)<<4))) = kx;
      const unsigned vw[4] = {vx.x, vx.y, vx.z, vx.w};
#pragma unroll
      for (int i = 0; i < 8; ++i) {
        const int h = hs*8 + i;
        const u16 val = (u16)(vw[i>>1] >> ((i&1)*16));
        *(u16*)((char*)&Vt[h*192] + ((m*2) ^ (((h>>3)&7)<<4))) = val;
      }
    }
  }

  bf16x8 qb[4][2];
  {
    const u16* qbase = qkv + ((size_t)(b*TL + l0)*5120 + (kh*8 + g)*64);
#pragma unroll
    for (int l4 = 0; l4 < 4; ++l4)
#pragma unroll
      for (int kk = 0; kk < 2; ++kk)
        qb[l4][kk] = *(const bf16x8*)(qbase + (size_t)(l4*16 + lL)*5120 + kk*32 + q*8);
  }
  const float sink = sinks[kh*8 + g];
  __syncthreads();

  float Mrun[4] = {-1e30f,-1e30f,-1e30f,-1e30f};
  float Dden[4] = {0.f,0.f,0.f,0.f};
  f32x4 oacc[4][4];
#pragma unroll
  for (int i = 0; i < 4; ++i)
#pragma unroll
    for (int j = 0; j < 4; ++j) oacc[i][j] = (f32x4){0.f,0.f,0.f,0.f};

  u16* Pw = &Pl[g][0];

  for (int c = 0; c < NC; ++c) {
    bf16x8 ka[2][2];
#pragma unroll
    for (int m2 = 0; m2 < 2; ++m2) {
      const int row = c*32 + m2*16 + lL;
#pragma unroll
      for (int kk = 0; kk < 2; ++kk)
        ka[m2][kk] = *(const bf16x8*)((char*)&Kl[row*64] +
                       ((kk*64 + q*16) ^ ((row&7)<<4)));
    }
    bf16x8 vb[4];
#pragma unroll
    for (int hf = 0; hf < 4; ++hf) {
      const int h = hf*16 + lL;
      vb[hf] = *(const bf16x8*)((char*)&Vt[h*192] +
                 ((c*64 + q*16) ^ (((h>>3)&7)<<4)));
    }

#pragma unroll
    for (int l4 = 0; l4 < 4; ++l4) {
      const int lo = base + l4*16;
      if (c*32 > lo + 15 || c*32 + 31 < lo - 127) continue;

      const f32x4 z = (f32x4){0.f,0.f,0.f,0.f};
      f32x4 s0 = __builtin_amdgcn_mfma_f32_16x16x32_bf16(ka[0][0], qb[l4][0], z, 0,0,0);
      s0 = __builtin_amdgcn_mfma_f32_16x16x32_bf16(ka[0][1], qb[l4][1], s0, 0,0,0);
      f32x4 s1 = __builtin_amdgcn_mfma_f32_16x16x32_bf16(ka[1][0], qb[l4][0], z, 0,0,0);
      s1 = __builtin_amdgcn_mfma_f32_16x16x32_bf16(ka[1][1], qb[l4][1], s1, 0,0,0);

      float sv[2][4];
      bool  al[2][4];
      float cmax = -1e30f;
#pragma unroll
      for (int m2 = 0; m2 < 2; ++m2)
#pragma unroll
        for (int j = 0; j < 4; ++j) {
          const int delta = (lo + lL) - (c*32 + m2*16 + q*4 + j);
          const bool a = (delta >= 0) && (delta < TWIN);
          const float s = (m2 ? s1[j] : s0[j]);
          sv[m2][j] = s;
          al[m2][j] = a;
          if (a) cmax = fmaxf(cmax, s);
        }
      cmax = fmaxf(cmax, __shfl_xor(cmax, 16));
      cmax = fmaxf(cmax, __shfl_xor(cmax, 32));
      const float Mn = fmaxf(Mrun[l4], cmax);
      const float r = __expf(Mrun[l4] - Mn);
      Mrun[l4] = Mn;

      float ls = 0.f;
      u16 pb[2][4];
#pragma unroll
      for (int m2 = 0; m2 < 2; ++m2)
#pragma unroll
        for (int j = 0; j < 4; ++j) {
          const float p = al[m2][j] ? __expf(sv[m2][j] - Mn) : 0.f;
          ls += p;
          pb[m2][j] = f2b(p);
        }
      ls += __shfl_xor(ls, 16);
      ls += __shfl_xor(ls, 32);
      Dden[l4] = Dden[l4]*r + ls;

      const int l = l4*16 + lL;
#pragma unroll
      for (int m2 = 0; m2 < 2; ++m2) {
        uint2 w;
        w.x = (unsigned)pb[m2][0] | ((unsigned)pb[m2][1] << 16);
        w.y = (unsigned)pb[m2][2] | ((unsigned)pb[m2][3] << 16);
        *(uint2*)((char*)Pw + l*64 + ((m2*32 + q*8) ^ ((l&3)<<4))) = w;
      }

      float rb[4];
#pragma unroll
      for (int j = 0; j < 4; ++j) rb[j] = __shfl(r, q*4 + j);
#pragma unroll
      for (int hf = 0; hf < 4; ++hf)
#pragma unroll
        for (int j = 0; j < 4; ++j) oacc[l4][hf][j] *= rb[j];

      bf16x8 pa = *(const bf16x8*)((char*)Pw + l*64 + ((q*16) ^ ((l&3)<<4)));
#pragma unroll
      for (int hf = 0; hf < 4; ++hf)
        oacc[l4][hf] = __builtin_amdgcn_mfma_f32_16x16x32_bf16(
            pa, vb[hf], oacc[l4][hf], 0, 0, 0);
    }
  }

#pragma unroll
  for (int l4 = 0; l4 < 4; ++l4) {
    const float di = 1.0f / (Dden[l4] + __expf(sink - Mrun[l4]));
    float db[4];
#pragma unroll
    for (int j = 0; j < 4; ++j) db[j] = __shfl(di, q*4 + j);
#pragma unroll
    for (int hf = 0; hf < 4; ++hf)
#pragma unroll
      for (int j = 0; j < 4; ++j) {
        const int row = l0 + l4*16 + q*4 + j;
        obuf[(size_t)(b*TL + row)*4096 + (kh*8 + g)*64 + hf*16 + lL] =
            f2b(oacc[l4][hf][j] * db[j]);
      }
  }
}

// ---------------------------------------------------------------------------
extern "C" void kernel_launch(void* const* d_in, const int* in_sizes, int n_in,
                              void* d_out, int out_size, void* d_ws, size_t ws_size,
                              hipStream_t stream)
{
  const float* x     = (const float*)d_in[0];
  const float* wq    = (const float*)d_in[1];
  const float* bq    = (const float*)d_in[2];
  const float* wk    = (const float*)d_in[3];
  const float* bk    = (const float*)d_in[4];
  const float* wv    = (const float*)d_in[5];
  const float* bv    = (const float*)d_in[6];
  const float* wo    = (const float*)d_in[7];
  const float* bo    = (const float*)d_in[8];
  const float* sinks = (const float*)d_in[9];
  const int* positions = (const int*)d_in[10];
  float* out = (float*)d_out;

  // layout identical to R2/R4/R9/R10 (103.2 MB — verified to fit)
  u16* xb    = (u16*)d_ws;
  u16* wqkvt = xb + (size_t)TT*TD;
  u16* wot   = wqkvt + (size_t)5120*TD;
  u16* qkv   = wot + (size_t)2944*4096;
  u16* obuf  = qkv + (size_t)TT*5120;
  float* bqkv = (float*)(obuf + (size_t)TT*4096);

  // fused preprocessing (1 launch)
  prep_kernel<<<31956, 256, 0, stream>>>(
      x, wq, wk, wv, wo, bq, bk, bv, xb, wqkvt, wot, bqkv);

  // fused QKV projection + bias + RoPE -> bf16 qkv [2048][5120]
  // R14: BN=128 tile — grid 16 rows x 40 cols = 640 blocks
  gemm_sn<128, 1><<<640, 256, 0, stream>>>(
      xb, wqkvt, bqkv, qkv, positions, TD, 5120, 5120, 1, 40);

  // MFMA flash attention -> obuf [2048][4096]
  attn3_kernel<<<dim3(8, TKH, TB), 512, 0, stream>>>(qkv, obuf, sinks);

  // output projection -> fp32 out [2048][2880]; 720 blocks (R13-verified)
  gemm_sn<64, 0><<<720, 256, 0, stream>>>(
      obuf, wot, bo, out, nullptr, 4096, 2880, 2880, 0, 45);
}